// Round 4
// baseline (695.351 us; speedup 1.0000x reference)
//
#include <hip/hip_runtime.h>

// Problem constants (from reference)
#define N_PTS 8388608
#define FX 758.03967f
#define CXC 621.46572f
#define FY 761.62359f
#define CYC 756.86402f
#define U_MAX 1231.0f   // WIDTH - 1
#define W_MAX 1615.0f   // HEIGHT - 1
#define MIN_D 1.0f
#define MAX_D_R 10.0f
#define MAX_D_M 5.0f

#define N_SLOTS 64
#define SLOT_STRIDE 32   // floats -> 128 B, one cacheline per slot (kills cross-slot contention)
#define N_BLOCKS (N_PTS / 4 / 256)   // 8192

// Workspace layout (uints):
//   [14]                      : block-completion ticket counter
//   [16 + i*SLOT_STRIDE]      : (i in [0,64)) partial counters
// ws is re-poisoned 0xAA each call -> everything we accumulate into must be
// zeroed by init_kernel first (same stream => ordered before frustum).

__global__ void init_kernel(float* __restrict__ ws) {
    int tid = threadIdx.x;
    if (tid < N_SLOTS) ((unsigned int*)ws)[16 + tid * SLOT_STRIDE] = 0u;
    if (tid == 0)      ((unsigned int*)ws)[14] = 0u;
}

__global__ __launch_bounds__(256) void frustum_kernel(const float4* __restrict__ pts,
                                                      const float* __restrict__ x,
                                                      const float* __restrict__ y,
                                                      const float* __restrict__ z,
                                                      const float* __restrict__ roll,
                                                      const float* __restrict__ pitch,
                                                      const float* __restrict__ yaw,
                                                      float* __restrict__ ws,
                                                      float4* __restrict__ out) {
    // Per-block pose setup: thread 0 computes R (bit-identical expressions to
    // the old pose_setup_kernel) into LDS; everyone reads after the sync.
    __shared__ float S[12];

    const int tid = blockIdx.x * 256 + threadIdx.x;   // one thread = 4 points = 3 float4
    const long base = (long)tid * 3;
    // Issue the global loads FIRST so their latency hides the trig + sync.
    float4 q0 = pts[base + 0];
    float4 q1 = pts[base + 1];
    float4 q2 = pts[base + 2];

    if (threadIdx.x == 0) {
        float cr = cosf(*roll), sr = sinf(*roll);
        float cp = cosf(*pitch), sp = sinf(*pitch);
        float cy = cosf(*yaw),  sy = sinf(*yaw);
        // R = Rx(roll) @ Ry(pitch) @ Rz(yaw), row-major. At the zero pose this is
        // exactly identity (with signed zeros), so v = points bit-exact.
        S[0] = cp * cy;                S[1] = -(cp * sy);             S[2] = sp;
        S[3] = cr * sy + sr * sp * cy; S[4] = cr * cy - sr * sp * sy; S[5] = -(sr * cp);
        S[6] = sr * sy - cr * sp * cy; S[7] = sr * cy + cr * sp * sy; S[8] = cr * cp;
        S[9] = *x; S[10] = *y; S[11] = *z;
    }
    __syncthreads();

    const float R0 = S[0], R1 = S[1], R2 = S[2];
    const float R3 = S[3], R4 = S[4], R5 = S[5];
    const float R6 = S[6], R7 = S[7], R8 = S[8];
    const float t0 = S[9], t1 = S[10], t2 = S[11];

    int cnt = 0;
    auto proc = [&](float px, float py, float pz, float& ox, float& oy, float& oz) {
        float d0 = px - t0, d1 = py - t1, d2 = pz - t2;
        // ascending-k fma accumulation to match the numpy reference's matmul
        float v0 = fmaf(d2, R6, fmaf(d1, R3, d0 * R0));
        float v1 = fmaf(d2, R7, fmaf(d1, R4, d0 * R1));
        float v2 = fmaf(d2, R8, fmaf(d1, R5, d0 * R2));
        float p0 = fmaf(v2, CXC, v0 * FX);
        float p1 = fmaf(v2, CYC, v1 * FY);
        float u = p0 / v2;           // IEEE div; inf/nan on v2==0 compares false, same as numpy mask
        float w = p1 / v2;
        bool fov = (v2 > 0.0f) && (u > 1.0f) && (u < U_MAX) && (w > 1.0f) && (w < W_MAX);
        if (fov && (v2 > MIN_D) && (v2 < MAX_D_R)) cnt++;
        bool m = fov && (v2 > MIN_D) && (v2 < MAX_D_M);
        ox = m ? v0 : 0.0f;
        oy = m ? v1 : 0.0f;
        oz = m ? v2 : 0.0f;
    };

    float4 o0, o1, o2;
    proc(q0.x, q0.y, q0.z, o0.x, o0.y, o0.z);   // point 0
    proc(q0.w, q1.x, q1.y, o0.w, o1.x, o1.y);   // point 1
    proc(q1.z, q1.w, q2.x, o1.z, o1.w, o2.x);   // point 2
    proc(q2.y, q2.z, q2.w, o2.y, o2.z, o2.w);   // point 3

    // Plain cached stores. R3 post-mortem: nontemporal stores amplified
    // WRITE_SIZE 1.74x (175 MB vs 101 MB ideal) and throttled the write path
    // (2.4 TB/s, 30% peak) -- nt bypasses L2 write-combining on gfx950.
    out[base + 0] = o0;
    out[base + 1] = o1;
    out[base + 2] = o2;

    // wave reduce (wave = 64), then block reduce in LDS, then ONE atomic per
    // block into one of 64 cacheline-spaced slots. Single-address atomic
    // (32K waves -> 1 address) serialized at L2 and cost ~370 us in R1.
    for (int off = 32; off > 0; off >>= 1) cnt += __shfl_down(cnt, off, 64);
    __shared__ int red[4];
    const int wave = threadIdx.x >> 6;
    if ((threadIdx.x & 63) == 0) red[wave] = cnt;
    __syncthreads();
    if (threadIdx.x == 0) {
        int s = red[0] + red[1] + red[2] + red[3];
        unsigned int* slots = (unsigned int*)ws + 16;
        if (s > 0) {
            atomicAdd(slots + (blockIdx.x & (N_SLOTS - 1)) * SLOT_STRIDE, (unsigned int)s);
        }
        // Fused finalize: last block to complete sums the slots and writes the
        // loss. Release: threadfence orders our slot-add before the ticket.
        __threadfence();
        unsigned int ticket = atomicAdd((unsigned int*)ws + 14, 1u);
        if (ticket == (unsigned int)(gridDim.x - 1)) {
            __threadfence();   // acquire side
            unsigned int c = 0;
            for (int i = 0; i < N_SLOTS; ++i)
                c += __hip_atomic_load(slots + i * SLOT_STRIDE,
                                       __ATOMIC_RELAXED, __HIP_MEMORY_SCOPE_AGENT);
            ((float*)out)[(long)3 * N_PTS] = 1.0f / ((float)c + 1e-6f);
        }
    }
}

extern "C" void kernel_launch(void* const* d_in, const int* in_sizes, int n_in,
                              void* d_out, int out_size, void* d_ws, size_t ws_size,
                              hipStream_t stream) {
    const float* points = (const float*)d_in[0];
    const float* x      = (const float*)d_in[1];
    const float* y      = (const float*)d_in[2];
    const float* z      = (const float*)d_in[3];
    const float* roll   = (const float*)d_in[4];
    const float* pitch  = (const float*)d_in[5];
    const float* yaw    = (const float*)d_in[6];
    float* ws = (float*)d_ws;
    float* out = (float*)d_out;

    init_kernel<<<1, 64, 0, stream>>>(ws);

    const int threads = 256;
    frustum_kernel<<<N_BLOCKS, threads, 0, stream>>>((const float4*)points,
                                                     x, y, z, roll, pitch, yaw,
                                                     ws, (float4*)out);
}

// Round 5
// 196.887 us; speedup vs baseline: 3.5317x; 3.5317x over previous
//
#include <hip/hip_runtime.h>

// Problem constants (from reference)
#define N_PTS 8388608
#define FX 758.03967f
#define CXC 621.46572f
#define FY 761.62359f
#define CYC 756.86402f
#define U_MAX 1231.0f   // WIDTH - 1
#define W_MAX 1615.0f   // HEIGHT - 1
#define MIN_D 1.0f
#define MAX_D_R 10.0f
#define MAX_D_M 5.0f

#define N_SLOTS 64
#define SLOT_STRIDE 32   // floats -> 128 B, one cacheline per slot (kills cross-slot contention)

// Workspace layout (floats):
//   [0..8]   R row-major
//   [9..11]  t
//   [16 + i*SLOT_STRIDE]  (i in [0,64))  : uint partial counters
//
// R4 lesson (counters): fused last-block finalize w/ __threadfence + single
// ticket atomic serialized the whole kernel (96 -> 571 us, same bytes).
// R3/R4 lesson: WRITE_SIZE ~180 MB regardless of nt/plain stores with
// FETCH ~49 MB -> the extra ~85 MB of writes is almost certainly the
// harness's async SDMA 0xAA re-poison of `out` landing in our counter
// window, not kernel traffic. Keep the 3-kernel structure.

__global__ void pose_setup_kernel(const float* __restrict__ x, const float* __restrict__ y,
                                  const float* __restrict__ z, const float* __restrict__ roll,
                                  const float* __restrict__ pitch, const float* __restrict__ yaw,
                                  float* __restrict__ ws) {
    int tid = threadIdx.x;
    if (tid == 0) {
        float cr = cosf(*roll), sr = sinf(*roll);
        float cp = cosf(*pitch), sp = sinf(*pitch);
        float cy = cosf(*yaw),  sy = sinf(*yaw);
        // R = Rx(roll) @ Ry(pitch) @ Rz(yaw), row-major. At the zero pose this is
        // exactly identity (with signed zeros), so v = points bit-exact.
        ws[0] = cp * cy;                ws[1] = -(cp * sy);             ws[2] = sp;
        ws[3] = cr * sy + sr * sp * cy; ws[4] = cr * cy - sr * sp * sy; ws[5] = -(sr * cp);
        ws[6] = sr * sy - cr * sp * cy; ws[7] = sr * cy + cr * sp * sy; ws[8] = cr * cp;
        ws[9] = *x; ws[10] = *y; ws[11] = *z;
    }
    if (tid < N_SLOTS) {
        ((unsigned int*)ws)[16 + tid * SLOT_STRIDE] = 0u;   // ws is re-poisoned 0xAA each call
    }
}

__global__ __launch_bounds__(256) void frustum_kernel(const float4* __restrict__ pts,
                                                      const float* __restrict__ ws,
                                                      float4* __restrict__ out) {
    const float R0 = ws[0], R1 = ws[1], R2 = ws[2];
    const float R3 = ws[3], R4 = ws[4], R5 = ws[5];
    const float R6 = ws[6], R7 = ws[7], R8 = ws[8];
    const float t0 = ws[9], t1 = ws[10], t2 = ws[11];

    const int tid = blockIdx.x * 256 + threadIdx.x;   // one thread = 4 points = 3 float4
    const long base = (long)tid * 3;
    float4 q0 = pts[base + 0];
    float4 q1 = pts[base + 1];
    float4 q2 = pts[base + 2];

    int cnt = 0;
    auto proc = [&](float px, float py, float pz, float& ox, float& oy, float& oz) {
        float d0 = px - t0, d1 = py - t1, d2 = pz - t2;
        // ascending-k fma accumulation to match the numpy reference's matmul
        float v0 = fmaf(d2, R6, fmaf(d1, R3, d0 * R0));
        float v1 = fmaf(d2, R7, fmaf(d1, R4, d0 * R1));
        float v2 = fmaf(d2, R8, fmaf(d1, R5, d0 * R2));
        float p0 = fmaf(v2, CXC, v0 * FX);
        float p1 = fmaf(v2, CYC, v1 * FY);
        float u = p0 / v2;           // IEEE div; inf/nan on v2==0 compares false, same as numpy mask
        float w = p1 / v2;
        bool fov = (v2 > 0.0f) && (u > 1.0f) && (u < U_MAX) && (w > 1.0f) && (w < W_MAX);
        if (fov && (v2 > MIN_D) && (v2 < MAX_D_R)) cnt++;
        bool m = fov && (v2 > MIN_D) && (v2 < MAX_D_M);
        ox = m ? v0 : 0.0f;
        oy = m ? v1 : 0.0f;
        oz = m ? v2 : 0.0f;
    };

    float4 o0, o1, o2;
    proc(q0.x, q0.y, q0.z, o0.x, o0.y, o0.z);   // point 0
    proc(q0.w, q1.x, q1.y, o0.w, o1.x, o1.y);   // point 1
    proc(q1.z, q1.w, q2.x, o1.z, o1.w, o2.x);   // point 2
    proc(q2.y, q2.z, q2.w, o2.y, o2.z, o2.w);   // point 3

    out[base + 0] = o0;
    out[base + 1] = o1;
    out[base + 2] = o2;

    // wave reduce (wave = 64), then block reduce in LDS, then ONE atomic per
    // block into one of 64 cacheline-spaced slots. R1's single-address atomic
    // (32K waves -> 1 address) serialized at L2 and cost ~370 us.
    for (int off = 32; off > 0; off >>= 1) cnt += __shfl_down(cnt, off, 64);
    __shared__ int red[4];
    const int wave = threadIdx.x >> 6;
    if ((threadIdx.x & 63) == 0) red[wave] = cnt;
    __syncthreads();
    if (threadIdx.x == 0) {
        int s = red[0] + red[1] + red[2] + red[3];
        if (s > 0) {
            unsigned int* slot = (unsigned int*)ws + 16 + (blockIdx.x & (N_SLOTS - 1)) * SLOT_STRIDE;
            atomicAdd(slot, (unsigned int)s);
        }
    }
}

__global__ void finalize_kernel(const float* __restrict__ ws, float* __restrict__ out) {
    unsigned int c = 0;
    for (int i = 0; i < N_SLOTS; ++i)
        c += ((const unsigned int*)ws)[16 + i * SLOT_STRIDE];
    out[(long)3 * N_PTS] = 1.0f / ((float)c + 1e-6f);
}

extern "C" void kernel_launch(void* const* d_in, const int* in_sizes, int n_in,
                              void* d_out, int out_size, void* d_ws, size_t ws_size,
                              hipStream_t stream) {
    const float* points = (const float*)d_in[0];
    const float* x      = (const float*)d_in[1];
    const float* y      = (const float*)d_in[2];
    const float* z      = (const float*)d_in[3];
    const float* roll   = (const float*)d_in[4];
    const float* pitch  = (const float*)d_in[5];
    const float* yaw    = (const float*)d_in[6];
    float* ws = (float*)d_ws;
    float* out = (float*)d_out;

    pose_setup_kernel<<<1, 64, 0, stream>>>(x, y, z, roll, pitch, yaw, ws);

    const int threads = 256;
    const int n_thread_units = N_PTS / 4;            // 4 points per thread
    const int blocks = n_thread_units / threads;     // 8192
    frustum_kernel<<<blocks, threads, 0, stream>>>((const float4*)points, ws, (float4*)out);

    finalize_kernel<<<1, 1, 0, stream>>>(ws, out);
}

// Round 6
// 192.108 us; speedup vs baseline: 3.6196x; 1.0249x over previous
//
#include <hip/hip_runtime.h>

// Problem constants (from reference)
#define N_PTS 8388608
#define FX 758.03967f
#define CXC 621.46572f
#define FY 761.62359f
#define CYC 756.86402f
#define U_MAX 1231.0f   // WIDTH - 1
#define W_MAX 1615.0f   // HEIGHT - 1
#define MIN_D 1.0f
#define MAX_D_R 10.0f
#define MAX_D_M 5.0f

#define N_SLOTS 64
#define SLOT_STRIDE 32   // floats -> 128 B, one cacheline per slot (kills cross-slot contention)

// Workspace layout (floats):
//   [0..8]   R row-major
//   [9..11]  t
//   [16 + i*SLOT_STRIDE]  (i in [0,64))  : uint partial counters
//
// R5 counters (baseline, 3-kernel, plain stores): frustum 62us, FETCH 49.7MB,
// WRITE 98.7MB (=ideal), 2.45 TB/s eff (39% of achievable), VALUBusy 18%.
// Not byte-bound: the tid*3 float4 indexing strides 48B across lanes, so every
// global load/store instruction touches 48 lines at 1/3 utilization (3x the
// transactions). This round: LDS-stage both directions so all global accesses
// are lane-contiguous; per-thread LDS access at 48B stride is bank-conflict-free
// for b128 (lanes 0..7 cover all 32 banks exactly once).
// R4 lesson: fused last-block finalize w/ __threadfence serialized everything
// (571us). R3 lesson: nontemporal stores amplify WRITE 1.74x. Keep 3 kernels,
// plain cached stores.

__global__ void pose_setup_kernel(const float* __restrict__ x, const float* __restrict__ y,
                                  const float* __restrict__ z, const float* __restrict__ roll,
                                  const float* __restrict__ pitch, const float* __restrict__ yaw,
                                  float* __restrict__ ws) {
    int tid = threadIdx.x;
    if (tid == 0) {
        float cr = cosf(*roll), sr = sinf(*roll);
        float cp = cosf(*pitch), sp = sinf(*pitch);
        float cy = cosf(*yaw),  sy = sinf(*yaw);
        // R = Rx(roll) @ Ry(pitch) @ Rz(yaw), row-major. At the zero pose this is
        // exactly identity (with signed zeros), so v = points bit-exact.
        ws[0] = cp * cy;                ws[1] = -(cp * sy);             ws[2] = sp;
        ws[3] = cr * sy + sr * sp * cy; ws[4] = cr * cy - sr * sp * sy; ws[5] = -(sr * cp);
        ws[6] = sr * sy - cr * sp * cy; ws[7] = sr * cy + cr * sp * sy; ws[8] = cr * cp;
        ws[9] = *x; ws[10] = *y; ws[11] = *z;
    }
    if (tid < N_SLOTS) {
        ((unsigned int*)ws)[16 + tid * SLOT_STRIDE] = 0u;   // ws is re-poisoned 0xAA each call
    }
}

__global__ __launch_bounds__(256) void frustum_kernel(const float4* __restrict__ pts,
                                                      const float* __restrict__ ws,
                                                      float4* __restrict__ out) {
    const float R0 = ws[0], R1 = ws[1], R2 = ws[2];
    const float R3 = ws[3], R4 = ws[4], R5 = ws[5];
    const float R6 = ws[6], R7 = ws[7], R8 = ws[8];
    const float t0 = ws[9], t1 = ws[10], t2 = ws[11];

    // 256 threads x 4 points = 1024 points = 768 float4 = 12 KB per block.
    __shared__ float4 st[768];

    const int t = threadIdx.x;
    const long gbase = (long)blockIdx.x * 768;   // block's first float4 index

    // Coalesced stage-in: lane-contiguous 16B, 3 fully-dense 1KB wave loads.
    st[t]       = pts[gbase + t];
    st[t + 256] = pts[gbase + t + 256];
    st[t + 512] = pts[gbase + t + 512];
    __syncthreads();

    // Thread t owns floats [12t, 12t+12) of the block = same global points as
    // the R5 baseline mapping (block*3072 + 12t), so cnt/out are bit-identical.
    const float4* pv = (const float4*)((const float*)st + t * 12);
    float4 q0 = pv[0];
    float4 q1 = pv[1];
    float4 q2 = pv[2];

    int cnt = 0;
    auto proc = [&](float px, float py, float pz, float& ox, float& oy, float& oz) {
        float d0 = px - t0, d1 = py - t1, d2 = pz - t2;
        // ascending-k fma accumulation to match the numpy reference's matmul
        float v0 = fmaf(d2, R6, fmaf(d1, R3, d0 * R0));
        float v1 = fmaf(d2, R7, fmaf(d1, R4, d0 * R1));
        float v2 = fmaf(d2, R8, fmaf(d1, R5, d0 * R2));
        float p0 = fmaf(v2, CXC, v0 * FX);
        float p1 = fmaf(v2, CYC, v1 * FY);
        float u = p0 / v2;           // IEEE div; inf/nan on v2==0 compares false, same as numpy mask
        float w = p1 / v2;
        bool fov = (v2 > 0.0f) && (u > 1.0f) && (u < U_MAX) && (w > 1.0f) && (w < W_MAX);
        if (fov && (v2 > MIN_D) && (v2 < MAX_D_R)) cnt++;
        bool m = fov && (v2 > MIN_D) && (v2 < MAX_D_M);
        ox = m ? v0 : 0.0f;
        oy = m ? v1 : 0.0f;
        oz = m ? v2 : 0.0f;
    };

    float4 o0, o1, o2;
    proc(q0.x, q0.y, q0.z, o0.x, o0.y, o0.z);   // point 0
    proc(q0.w, q1.x, q1.y, o0.w, o1.x, o1.y);   // point 1
    proc(q1.z, q1.w, q2.x, o1.z, o1.w, o2.x);   // point 2
    proc(q2.y, q2.z, q2.w, o2.y, o2.z, o2.w);   // point 3

    // In-place writeback of my own 48B region (no cross-thread hazard).
    float4* wv = (float4*)((float*)st + t * 12);
    wv[0] = o0;
    wv[1] = o1;
    wv[2] = o2;
    __syncthreads();

    // Coalesced stage-out.
    out[gbase + t]       = st[t];
    out[gbase + t + 256] = st[t + 256];
    out[gbase + t + 512] = st[t + 512];

    // wave reduce (wave = 64), then block reduce in LDS, then ONE atomic per
    // block into one of 64 cacheline-spaced slots. R1's single-address atomic
    // (32K waves -> 1 address) serialized at L2 and cost ~370 us.
    for (int off = 32; off > 0; off >>= 1) cnt += __shfl_down(cnt, off, 64);
    __shared__ int red[4];
    const int wave = threadIdx.x >> 6;
    if ((threadIdx.x & 63) == 0) red[wave] = cnt;
    __syncthreads();
    if (threadIdx.x == 0) {
        int s = red[0] + red[1] + red[2] + red[3];
        if (s > 0) {
            unsigned int* slot = (unsigned int*)ws + 16 + (blockIdx.x & (N_SLOTS - 1)) * SLOT_STRIDE;
            atomicAdd(slot, (unsigned int)s);
        }
    }
}

__global__ void finalize_kernel(const float* __restrict__ ws, float* __restrict__ out) {
    unsigned int c = 0;
    for (int i = 0; i < N_SLOTS; ++i)
        c += ((const unsigned int*)ws)[16 + i * SLOT_STRIDE];
    out[(long)3 * N_PTS] = 1.0f / ((float)c + 1e-6f);
}

extern "C" void kernel_launch(void* const* d_in, const int* in_sizes, int n_in,
                              void* d_out, int out_size, void* d_ws, size_t ws_size,
                              hipStream_t stream) {
    const float* points = (const float*)d_in[0];
    const float* x      = (const float*)d_in[1];
    const float* y      = (const float*)d_in[2];
    const float* z      = (const float*)d_in[3];
    const float* roll   = (const float*)d_in[4];
    const float* pitch  = (const float*)d_in[5];
    const float* yaw    = (const float*)d_in[6];
    float* ws = (float*)d_ws;
    float* out = (float*)d_out;

    pose_setup_kernel<<<1, 64, 0, stream>>>(x, y, z, roll, pitch, yaw, ws);

    const int threads = 256;
    const int blocks = N_PTS / 1024;                 // 1024 points per block -> 8192
    frustum_kernel<<<blocks, threads, 0, stream>>>((const float4*)points, ws, (float4*)out);

    finalize_kernel<<<1, 1, 0, stream>>>(ws, out);
}